// Round 2
// baseline (188.907 us; speedup 1.0000x reference)
//
#include <hip/hip_runtime.h>
#include <stdint.h>

// conv_59700045414486: y[b,n,o] = sum_{k,c} x[b, kernel2[n,k], c] * W[k,c,o] + bias[o]
// B=64, N=4096, C=64, OUT=64, K2=4  -> per-site GEMM M=64 K=256 N=64
//
// R2: latency-bound fix (R1: MfmaUtil 3.4%, VALU 5%, hbm 41%, occ 38%, VGPR=64
//     -> serial gather latency). Changes:
//  1. Full-site load batching: all 16 gather loads (64 VGPRs) issued before any
//     convert/MFMA -> one latency exposure per site instead of ~8 serial.
//  2. MFMA operand swap: A=W (LDS), B=x (gather). D = [o][batch]; lane's 4 acc
//     regs = 4 consecutive o -> global_store_dwordx4 (was 16 scalar stores).
//  3. Next-site idx prefetch.
// __launch_bounds__(256,4) caps VGPR at 128 to keep LDS-limited 4 blocks/CU.

#define B_DIM        64
#define N_SITES      4096
#define C_DIM        64
#define OUT_DIM      64
#define SITES_PER_BLOCK 4
#define LDS_STRIDE   264   // 256 + 8 bf16 pad; measured cost ~1 cyc per ds_read_b128 (negligible)

typedef __attribute__((ext_vector_type(8))) short bf16x8;   // 8 bf16 in 4 VGPRs
typedef __attribute__((ext_vector_type(4))) float f32x4;

// round-to-nearest(+0.5ulp) fp32->bf16 for two floats, packed into one dword
__device__ __forceinline__ uint32_t pack2_bf16(float f0, float f1) {
    uint32_t u0 = __float_as_uint(f0) + 0x8000u;
    uint32_t u1 = __float_as_uint(f1) + 0x8000u;
    return __builtin_amdgcn_perm(u1, u0, 0x07060302u);  // [u1.hi16 | u0.hi16]
}

__global__ __launch_bounds__(256, 4)
void conv_mfma_kernel(const float* __restrict__ x, const float* __restrict__ W,
                      const float* __restrict__ bias, const int* __restrict__ kernel2,
                      float* __restrict__ out)
{
    __shared__ __align__(16) short wt[OUT_DIM * LDS_STRIDE];  // 33792 B

    const int tid  = threadIdx.x;
    const int wave = tid >> 6;       // batch strip [16*wave, 16*wave+16)
    const int lane = tid & 63;
    const int m    = lane & 15;      // A row (o), B col (batch), D col (batch)
    const int q    = lane >> 4;      // k-offset q*8; D row (o) = q*4+reg

    // ---- Stage W -> LDS as bf16, transposed: wt[o][kk], kk = k*64 + c ----
    {
        const int o      = tid & 63;
        const int kkbase = (tid >> 6) * 64;
        uint32_t* dst = (uint32_t*)&wt[o * LDS_STRIDE + kkbase];
        #pragma unroll
        for (int j = 0; j < 32; ++j) {
            float f0 = W[(size_t)(kkbase + 2*j    ) * OUT_DIM + o];  // coalesced over o
            float f1 = W[(size_t)(kkbase + 2*j + 1) * OUT_DIM + o];
            dst[j] = pack2_bf16(f0, f1);
        }
    }
    __syncthreads();

    // bias: lane's o values are t*16 + q*4 .. +3 (contiguous float4)
    f32x4 bias_r[4];
    #pragma unroll
    for (int t = 0; t < 4; ++t) bias_r[t] = *(const f32x4*)&bias[t*16 + q*4];

    // gather base: batch row (wave*16 + m), k-offset q*8 floats
    const float* xw = x + (size_t)(wave*16 + m) * (N_SITES * C_DIM) + q*8;

    const int site0 = blockIdx.x * SITES_PER_BLOCK;
    int4 idx = *(const int4*)(kernel2 + site0 * 4);

    for (int si = 0; si < SITES_PER_BLOCK; ++si) {
        const int n = site0 + si;
        const float* bps[4] = {
            xw + (size_t)idx.x * C_DIM,
            xw + (size_t)idx.y * C_DIM,
            xw + (size_t)idx.z * C_DIM,
            xw + (size_t)idx.w * C_DIM
        };

        // ---- issue ALL 16 gather loads for this site up front ----
        f32x4 lo[8], hi[8];
        #pragma unroll
        for (int s = 0; s < 8; ++s) {
            const float* p = bps[s >> 1] + (s & 1) * 32;
            lo[s] = *(const f32x4*)(p);
            hi[s] = *(const f32x4*)(p + 4);
        }

        // prefetch next site's indices while loads are in flight
        if (si + 1 < SITES_PER_BLOCK) idx = *(const int4*)(kernel2 + (n + 1) * 4);

        f32x4 acc[4];
        #pragma unroll
        for (int t = 0; t < 4; ++t) acc[t] = (f32x4){0.f, 0.f, 0.f, 0.f};

        // ---- convert + MFMA: K=256 in 8 steps of 32 ----
        #pragma unroll
        for (int s = 0; s < 8; ++s) {
            bf16x8 b;                              // B = gathered x, B[k][n=batch]
            uint32_t* bp = (uint32_t*)&b;
            bp[0] = pack2_bf16(lo[s][0], lo[s][1]);
            bp[1] = pack2_bf16(lo[s][2], lo[s][3]);
            bp[2] = pack2_bf16(hi[s][0], hi[s][1]);
            bp[3] = pack2_bf16(hi[s][2], hi[s][3]);

            const int col = s*32 + q*8;
            #pragma unroll
            for (int t = 0; t < 4; ++t) {
                // A = W-tile: A[m=o_local][k] -> wt[o = t*16+m][kk = col+j]
                bf16x8 a = *(const bf16x8*)&wt[(t*16 + m) * LDS_STRIDE + col];
                acc[t] = __builtin_amdgcn_mfma_f32_16x16x32_bf16(a, b, acc[t], 0, 0, 0);
            }
        }

        // ---- store: D col = batch = m, D row = o_local = q*4+reg ----
        // lane writes float4 at out[(wave*16+m)*N + n]*64 + t*16 + q*4
        float* op = out + ((size_t)(wave*16 + m) * N_SITES + n) * OUT_DIM + q*4;
        #pragma unroll
        for (int t = 0; t < 4; ++t) {
            f32x4 v;
            #pragma unroll
            for (int r = 0; r < 4; ++r) v[r] = acc[t][r] + bias_r[t][r];
            *(f32x4*)(op + t*16) = v;
        }
    }
}

extern "C" void kernel_launch(void* const* d_in, const int* in_sizes, int n_in,
                              void* d_out, int out_size, void* d_ws, size_t ws_size,
                              hipStream_t stream) {
    const float* x       = (const float*)d_in[0];
    const float* W       = (const float*)d_in[1];
    const float* bias    = (const float*)d_in[2];
    const int*   kernel2 = (const int*)d_in[3];
    float* out = (float*)d_out;

    conv_mfma_kernel<<<N_SITES / SITES_PER_BLOCK, 256, 0, stream>>>(x, W, bias, kernel2, out);
}

// Round 3
// 154.319 us; speedup vs baseline: 1.2241x; 1.2241x over previous
//
#include <hip/hip_runtime.h>
#include <stdint.h>

// conv_59700045414486: y[b,n,o] = sum_{k,c} x[b, kernel2[n,k], c] * W[k,c,o] + bias[o]
// B=64, N=4096, C=64, OUT=64, K2=4
//
// R3 theory: R1/R2 bound by L2-miss gather traffic (FETCH 200 MB == per-XCD
// compulsory model for full-batch blocks) + serialized loads (VGPR stuck at 64).
// Changes:
//  1. Batch-strip blocking: block = 4 batches x 16 sites. Strip pinned to XCD
//     via blockIdx%8 (16 strips, two grid halves) -> per-XCD gather working set
//     = 4 MB = L2 size. Gathers become L2-resident.
//  2. MFMA cols = (4 sites x 4 batches): one acc phase per wave for 4 sites.
//     16 payload loads issued BEFORE the W-stage (independent of LDS), pinned
//     with sched_barrier(0) -> latency hidden under W staging + barrier.
//  3. launch_bounds(256,3): VGPR cap 170 so the 64-reg payload can stay live.

#define N_SITES   4096
#define C_DIM     64
#define OUT_DIM   64
#define LDS_STRIDE 264   // 256 + 8 bf16 pad

typedef __attribute__((ext_vector_type(8))) short bf16x8;
typedef __attribute__((ext_vector_type(4))) float f32x4;

__device__ __forceinline__ uint32_t pack2_bf16(float f0, float f1) {
    uint32_t u0 = __float_as_uint(f0) + 0x8000u;
    uint32_t u1 = __float_as_uint(f1) + 0x8000u;
    return __builtin_amdgcn_perm(u1, u0, 0x07060302u);  // [bf16(f1) | bf16(f0)]
}

__global__ __launch_bounds__(256, 3)
void conv_mfma_kernel(const float* __restrict__ x, const float* __restrict__ W,
                      const float* __restrict__ bias, const int* __restrict__ kernel2,
                      float* __restrict__ out)
{
    __shared__ __align__(16) short wt[OUT_DIM * LDS_STRIDE];  // 33792 B

    const int tid = threadIdx.x;
    const int bi  = blockIdx.x;

    // 16 strips of 4 batches; strips 0-7 in first 2048 blocks (XCD = bi%8 = strip),
    // strips 8-15 in the second half. group = site tile.
    const int strip = (bi & 7) + ((bi >= 2048) ? 8 : 0);
    const int group = (bi & 2047) >> 3;            // 0..255
    const int n0 = group * 16;
    const int b0 = strip * 4;

    const int wave = tid >> 6;
    const int lane = tid & 63;
    const int q = lane >> 4;        // k-quad; D row (o) = q*4+reg
    const int c = lane & 15;        // MFMA column = (site_local, batch_local)
    const int sl = c >> 2;          // site within wave's quad
    const int b  = b0 + (c & 3);    // batch

    // ---- gather payload: issue all 16 loads up front, before W staging ----
    const int n = n0 + wave * 4 + sl;
    const int4 idx = *(const int4*)(kernel2 + n * 4);
    const float* xb = x + (size_t)b * (N_SITES * C_DIM);
    const float* rp[4] = {
        xb + (size_t)idx.x * C_DIM,
        xb + (size_t)idx.y * C_DIM,
        xb + (size_t)idx.z * C_DIM,
        xb + (size_t)idx.w * C_DIM
    };

    f32x4 pay[16];
    #pragma unroll
    for (int s = 0; s < 8; ++s) {
        const float* p = rp[s >> 1] + (s & 1) * 32 + q * 8;
        pay[2*s]     = *(const f32x4*)(p);
        pay[2*s + 1] = *(const f32x4*)(p + 4);
    }

    f32x4 bias_r[4];
    #pragma unroll
    for (int t = 0; t < 4; ++t) bias_r[t] = *(const f32x4*)&bias[t*16 + q*4];

    // keep the payload loads ahead of everything below
    __builtin_amdgcn_sched_barrier(0);

    // ---- stage W -> LDS as bf16, transposed: wt[o][kk], kk = k*64 + c ----
    {
        const int o      = tid & 63;
        const int kkbase = (tid >> 6) * 64;
        uint32_t* dst = (uint32_t*)&wt[o * LDS_STRIDE + kkbase];
        #pragma unroll
        for (int j = 0; j < 32; ++j) {
            float f0 = W[(size_t)(kkbase + 2*j    ) * OUT_DIM + o];  // coalesced over o
            float f1 = W[(size_t)(kkbase + 2*j + 1) * OUT_DIM + o];
            dst[j] = pack2_bf16(f0, f1);
        }
    }
    __syncthreads();

    // ---- compute: K=256 in 8 steps of 32; one acc phase covers 4 sites ----
    f32x4 acc[4];
    #pragma unroll
    for (int t = 0; t < 4; ++t) acc[t] = (f32x4){0.f, 0.f, 0.f, 0.f};

    #pragma unroll
    for (int s = 0; s < 8; ++s) {
        bf16x8 bfrag;                       // B[k][col]: col = c, k = q*8+j
        uint32_t* bp = (uint32_t*)&bfrag;
        bp[0] = pack2_bf16(pay[2*s][0],   pay[2*s][1]);
        bp[1] = pack2_bf16(pay[2*s][2],   pay[2*s][3]);
        bp[2] = pack2_bf16(pay[2*s+1][0], pay[2*s+1][1]);
        bp[3] = pack2_bf16(pay[2*s+1][2], pay[2*s+1][3]);

        const int col = s*32 + q*8;
        #pragma unroll
        for (int t = 0; t < 4; ++t) {
            // A = W: lane holds A[row = c][k] -> wt[o = t*16+c][kk = col+j]
            bf16x8 a = *(const bf16x8*)&wt[(t*16 + c) * LDS_STRIDE + col];
            acc[t] = __builtin_amdgcn_mfma_f32_16x16x32_bf16(a, bfrag, acc[t], 0, 0, 0);
        }
    }

    // ---- store: D col = c -> (site sl, batch b); D row = o = t*16 + q*4 + r ----
    float* op = out + ((size_t)b * N_SITES + n) * OUT_DIM + q * 4;
    #pragma unroll
    for (int t = 0; t < 4; ++t) {
        f32x4 v;
        #pragma unroll
        for (int r = 0; r < 4; ++r) v[r] = acc[t][r] + bias_r[t][r];
        *(f32x4*)(op + t * 16) = v;
    }
}

extern "C" void kernel_launch(void* const* d_in, const int* in_sizes, int n_in,
                              void* d_out, int out_size, void* d_ws, size_t ws_size,
                              hipStream_t stream) {
    const float* x       = (const float*)d_in[0];
    const float* W       = (const float*)d_in[1];
    const float* bias    = (const float*)d_in[2];
    const int*   kernel2 = (const int*)d_in[3];
    float* out = (float*)d_out;

    // 16 strips x 256 site-groups = 4096 blocks
    conv_mfma_kernel<<<4096, 256, 0, stream>>>(x, W, bias, kernel2, out);
}

// Round 4
// 152.114 us; speedup vs baseline: 1.2419x; 1.0145x over previous
//
#include <hip/hip_runtime.h>
#include <stdint.h>

// conv_59700045414486: y[b,n,o] = sum_{k,c} x[b, kernel2[n,k], c] * W[k,c,o] + bias[o]
// B=64, N=4096, C=64, OUT=64, K2=4
//
// R4: R3 fixed traffic (hbm_bytes ~= compulsory 121 MB) but stayed latency-bound
// (1.9 TB/s, VGPR stuck at 64 => gathers serialized; short block life + barrier
// re-exposed latency per block). This round:
//  1. Block = 4 batches x 64 sites (4 phases of 16): W staged ONCE, no barrier
//     in the steady loop (LDS read-only after stage). Grid 1024 = 4 blocks/CU.
//  2. Half-phase software pipeline: compute half h (16 ds_read+16 MFMA ~800cy)
//     while the 8 gather dwordx4 loads of half h+1 fly. Peak regs ~112 < 128
//     cap of launch_bounds(256,4) -- a budget the allocator can honor.
//  3. idx prefetched two phases ahead; gather offsets as u32 byte-elt offsets.

#define N_SITES   4096
#define C_DIM     64
#define OUT_DIM   64
#define LDS_STRIDE 264   // 256+8 bf16 pad: (c*132)%32 = c*4 -> 2-way only (free)
#define P_PHASES  4      // 16 sites/phase -> 64 sites/block

typedef __attribute__((ext_vector_type(8))) short bf16x8;
typedef __attribute__((ext_vector_type(4))) float f32x4;

__device__ __forceinline__ uint32_t pack2_bf16(float f0, float f1) {
    uint32_t u0 = __float_as_uint(f0) + 0x8000u;
    uint32_t u1 = __float_as_uint(f1) + 0x8000u;
    return __builtin_amdgcn_perm(u1, u0, 0x07060302u);  // [bf16(f1)|bf16(f0)]
}

__global__ __launch_bounds__(256, 4)
void conv_mfma_kernel(const float* __restrict__ x, const float* __restrict__ W,
                      const float* __restrict__ bias, const int* __restrict__ kernel2,
                      float* __restrict__ out)
{
    __shared__ __align__(16) short wt[OUT_DIM * LDS_STRIDE];  // 33792 B

    const int tid = threadIdx.x;
    const int bi  = blockIdx.x;

    // 16 strips x 64 site-groups; bi&7 round-robins XCDs within each grid half
    const int strip = (bi & 7) + ((bi >= 512) ? 8 : 0);
    const int g     = (bi & 511) >> 3;          // 0..63
    const int n0    = g * 64;

    const int wave = tid >> 6;
    const int lane = tid & 63;
    const int q  = lane >> 4;        // k-quad; D row (o) = q*4+reg
    const int c  = lane & 15;        // MFMA column = (site_local, batch_local)
    const int sl = c >> 2;
    const int b  = strip * 4 + (c & 3);

    const int nbase = n0 + wave * 4 + sl;       // site for phase p: nbase + p*16

    // phase-0 indices: start the longest chain first
    int4 idx = *(const int4*)(kernel2 + nbase * 4);

    // ---- stage W -> LDS as bf16, wt[o][kk] (kk = k*64 + cin), once per block ----
    {
        const int o      = tid & 63;
        const int kkbase = (tid >> 6) * 64;
        uint32_t* dst = (uint32_t*)&wt[o * LDS_STRIDE + kkbase];
        #pragma unroll
        for (int j = 0; j < 32; ++j) {
            float f0 = W[(size_t)(kkbase + 2*j    ) * OUT_DIM + o];  // coalesced over o
            float f1 = W[(size_t)(kkbase + 2*j + 1) * OUT_DIM + o];
            dst[j] = pack2_bf16(f0, f1);
        }
    }

    f32x4 bias_r[4];
    #pragma unroll
    for (int t = 0; t < 4; ++t) bias_r[t] = *(const f32x4*)&bias[t*16 + q*4];

    const float* xq = x + (size_t)b * (N_SITES * C_DIM) + q * 8;

    // pipeline state
    f32x4    pay[8];     // in-flight half: 8 dwordx4 = 32 VGPRs
    uint32_t pk[16];     // packed current compute half
    uint32_t off[4];     // element offsets of the 4 neighbor rows

    auto build_off = [&](int4 v) {
        off[0] = (uint32_t)v.x * C_DIM; off[1] = (uint32_t)v.y * C_DIM;
        off[2] = (uint32_t)v.z * C_DIM; off[3] = (uint32_t)v.w * C_DIM;
    };
    auto load_half = [&](int h) {     // steps s' = h*4 .. h*4+3
        #pragma unroll
        for (int s = 0; s < 4; ++s) {
            const float* p = xq + off[h*2 + (s >> 1)] + (s & 1) * 32;
            pay[2*s]     = *(const f32x4*)(p);
            pay[2*s + 1] = *(const f32x4*)(p + 4);
        }
    };
    auto pack_half = [&]() {          // waits pay, frees it
        #pragma unroll
        for (int s = 0; s < 4; ++s) {
            pk[4*s+0] = pack2_bf16(pay[2*s][0],   pay[2*s][1]);
            pk[4*s+1] = pack2_bf16(pay[2*s][2],   pay[2*s][3]);
            pk[4*s+2] = pack2_bf16(pay[2*s+1][0], pay[2*s+1][1]);
            pk[4*s+3] = pack2_bf16(pay[2*s+1][2], pay[2*s+1][3]);
        }
    };

    build_off(idx);
    load_half(0);                                   // phase 0, half 0 in flight
    int4 idxn = *(const int4*)(kernel2 + (nbase + 16) * 4);   // phase 1 idx

    __syncthreads();                                // W visible; only barrier

    pack_half();                                    // pk = p0.h0
    load_half(1);                                   // p0.h1 in flight

    #pragma unroll
    for (int p = 0; p < P_PHASES; ++p) {
        const int n = nbase + p * 16;

        f32x4 acc[4];
        #pragma unroll
        for (int t = 0; t < 4; ++t) acc[t] = (f32x4){0.f, 0.f, 0.f, 0.f};

        // compute half 0 (pk) while half 1 flies
        #pragma unroll
        for (int s = 0; s < 4; ++s) {
            bf16x8 bf = *(const bf16x8*)&pk[4*s];
            const int col = s*32 + q*8;
            #pragma unroll
            for (int t = 0; t < 4; ++t) {
                bf16x8 a = *(const bf16x8*)&wt[(t*16 + c) * LDS_STRIDE + col];
                acc[t] = __builtin_amdgcn_mfma_f32_16x16x32_bf16(a, bf, acc[t], 0, 0, 0);
            }
        }

        pack_half();                                // pk = p.h1
        if (p + 1 < P_PHASES) {                     // start next phase h0
            build_off(idxn);
            load_half(0);
        }
        if (p + 2 < P_PHASES)
            idxn = *(const int4*)(kernel2 + (nbase + (p + 2) * 16) * 4);

        // compute half 1 (pk) while next phase's half 0 flies
        #pragma unroll
        for (int s = 0; s < 4; ++s) {
            bf16x8 bf = *(const bf16x8*)&pk[4*s];
            const int col = (4 + s)*32 + q*8;
            #pragma unroll
            for (int t = 0; t < 4; ++t) {
                bf16x8 a = *(const bf16x8*)&wt[(t*16 + c) * LDS_STRIDE + col];
                acc[t] = __builtin_amdgcn_mfma_f32_16x16x32_bf16(a, bf, acc[t], 0, 0, 0);
            }
        }

        if (p + 1 < P_PHASES) {
            pack_half();                            // pk = (p+1).h0
            load_half(1);                           // (p+1).h1 in flight
        }

        // store phase p: D col=c -> (site, batch); D row = o = t*16+q*4+r
        float* op = out + ((size_t)b * N_SITES + n) * OUT_DIM + q * 4;
        #pragma unroll
        for (int t = 0; t < 4; ++t) {
            f32x4 v;
            #pragma unroll
            for (int r = 0; r < 4; ++r) v[r] = acc[t][r] + bias_r[t][r];
            *(f32x4*)(op + t * 16) = v;
        }
    }
}

extern "C" void kernel_launch(void* const* d_in, const int* in_sizes, int n_in,
                              void* d_out, int out_size, void* d_ws, size_t ws_size,
                              hipStream_t stream) {
    const float* x       = (const float*)d_in[0];
    const float* W       = (const float*)d_in[1];
    const float* bias    = (const float*)d_in[2];
    const int*   kernel2 = (const int*)d_in[3];
    float* out = (float*)d_out;

    // 16 strips x 64 groups = 1024 blocks (= 4 blocks/CU, LDS-limited residency)
    conv_mfma_kernel<<<1024, 256, 0, stream>>>(x, W, bias, kernel2, out);
}

// Round 5
// 146.156 us; speedup vs baseline: 1.2925x; 1.0408x over previous
//
#include <hip/hip_runtime.h>
#include <stdint.h>

// conv_59700045414486: y[b,n,o] = sum_{k,c} x[b, kernel2[n,k], c] * W[k,c,o] + bias[o]
// B=64, N=4096, C=64, OUT=64, K2=4
//
// R5: compiler defeated VGPR-load pipelining 3x (VGPR stuck at 60-64, 2 TB/s
// latency-bound). Switch to register-free async gathers:
//   - global_load_lds DMA (inline asm, LDS base in M0): no dest VGPR -> the
//     register-pressure scheduler cannot serialize it; deep vmcnt queue.
//   - single-wave blocks (64 thr): NO __syncthreads in steady state; W held
//     in 128 VGPRs of A-fragments (loaded once); x tiles double-buffered in
//     LDS (2 x 16KB), depth-2 pipeline, manual s_waitcnt vmcnt(N).
//   - vmcnt queue = tile DMAs + output stores ONLY (idx staged to LDS in
//     prologue, read via ds_read -> lgkmcnt), so wait arithmetic is exact.
// Block = 4 batches x 64 sites (16 phases x 4 sites x 4 batches = MFMA cols).
// Grid 1024 = 4 blocks/CU co-resident (LDS 33.8KB), one generation.

#define N_SITES  4096
#define C_DIM    64
#define OUT_DIM  64

typedef __attribute__((ext_vector_type(8))) short bf16x8;
typedef __attribute__((ext_vector_type(4))) float f32x4;

__device__ __forceinline__ uint32_t pack2_bf16(float f0, float f1) {
    uint32_t u0 = __float_as_uint(f0) + 0x8000u;
    uint32_t u1 = __float_as_uint(f1) + 0x8000u;
    return __builtin_amdgcn_perm(u1, u0, 0x07060302u);  // [bf16(f1)|bf16(f0)]
}

template<int N> __device__ __forceinline__ void wait_vmcnt() {
    asm volatile("s_waitcnt vmcnt(%0)" :: "n"(N) : "memory");
}

// async 16B/lane global->LDS DMA; LDS dst = M0 + lane*16 (wave-uniform M0)
__device__ __forceinline__ void gll16(const float* p, uint32_t m0v) {
    asm volatile("s_mov_b32 m0, %1\n\t"
                 "global_load_lds_dwordx4 %0, off"
                 :: "v"(p), "s"(m0v) : "memory");
}

__global__ __launch_bounds__(64, 1)
void conv_async_kernel(const float* __restrict__ x, const float* __restrict__ W,
                       const float* __restrict__ bias, const int* __restrict__ kernel2,
                       float* __restrict__ out)
{
    // [0,32768): two 16KB x-tile slots; [32768,33792): 64 sites' idx (int4)
    __shared__ __align__(16) uint8_t lds_raw[33792];

    const int lane = threadIdx.x;          // 64 threads = 1 wave
    const int bi   = blockIdx.x;
    const int sg   = bi >> 4;              // 64 site-groups of 64 sites
    const int bg   = bi & 15;              // 16 batch-groups of 4 (bi%8 ~ XCD)
    const int n0   = sg * 64;
    const int b0   = bg * 4;

    const int c  = lane & 15;              // MFMA col = (site sl, batch bb)
    const int q  = lane >> 4;              // k-quad; D row (o) = q*4+reg
    const int sl = c >> 2;
    const int bb = c & 3;

    // ---- stage this block's kernel2 slice into LDS (so in-loop idx reads
    //      are ds_read/lgkmcnt, keeping the vmcnt queue = tiles+stores only)
    {
        int4 iv = ((const int4*)kernel2)[n0 + lane];
        *(int4*)(lds_raw + 32768 + lane * 16) = iv;
    }

    // ---- A-fragments of W in registers, for the whole kernel (128 VGPRs)
    // A[m=c][k=q*8+j] for o = t*16+c, kk-block s: aw[t][s]
    bf16x8 aw[4][8];
    #pragma unroll
    for (int t = 0; t < 4; ++t)
        #pragma unroll
        for (int s = 0; s < 8; ++s) {
            uint32_t* ap = (uint32_t*)&aw[t][s];
            #pragma unroll
            for (int u = 0; u < 4; ++u) {
                float f0 = W[(size_t)(s*32 + q*8 + 2*u    ) * OUT_DIM + t*16 + c];
                float f1 = W[(size_t)(s*32 + q*8 + 2*u + 1) * OUT_DIM + t*16 + c];
                ap[u] = pack2_bf16(f0, f1);
            }
        }

    f32x4 bias_r[4];
    #pragma unroll
    for (int t = 0; t < 4; ++t) bias_r[t] = *(const f32x4*)&bias[t*16 + q*4];

    // per-lane gather base: batch plane + this lane's 16B piece (pcq = q)
    const float* gx = x + (size_t)(b0 + bb) * (N_SITES * C_DIM) + q * 4;

    // LDS byte offset of lds_raw for M0 (flat shared ptr low bits = offset)
    const uint32_t lds0 =
        __builtin_amdgcn_readfirstlane((uint32_t)(uintptr_t)lds_raw);

    // drain prologue loads: vmcnt queue must start empty for exact counting
    wait_vmcnt<0>();

    // tile layout, slot d: instr i = ks*4+hs*2+j at d*16384 + i*1024;
    // lane w=pcq*16+c' holds row(c') bytes [hs*128 + pcq*16 + j*64, +16).
    // readback for s=ks*2+hs: b128 at s*2048 + q*512 + c*16 (+256).
    auto issue_tile = [&](int pp) {
        const uint8_t* ib = lds_raw + 32768 + pp * 64;
        int4 iv0 = *(const int4*)(ib);
        int4 iv1 = *(const int4*)(ib + 16);
        int4 iv2 = *(const int4*)(ib + 32);
        int4 iv3 = *(const int4*)(ib + 48);
        const uint32_t m0b = lds0 + (uint32_t)(pp & 1) * 16384;
        #pragma unroll
        for (int ks = 0; ks < 4; ++ks) {
            const int e0 = ks==0 ? iv0.x : ks==1 ? iv0.y : ks==2 ? iv0.z : iv0.w;
            const int e1 = ks==0 ? iv1.x : ks==1 ? iv1.y : ks==2 ? iv1.z : iv1.w;
            const int e2 = ks==0 ? iv2.x : ks==1 ? iv2.y : ks==2 ? iv2.z : iv2.w;
            const int e3 = ks==0 ? iv3.x : ks==1 ? iv3.y : ks==2 ? iv3.z : iv3.w;
            const int nk = (sl & 2) ? ((sl & 1) ? e3 : e2)
                                    : ((sl & 1) ? e1 : e0);
            const float* row = gx + (size_t)(uint32_t)nk * C_DIM;
            gll16(row,      m0b + (uint32_t)(ks*4 + 0) * 1024);  // hs0 j0
            gll16(row + 16, m0b + (uint32_t)(ks*4 + 1) * 1024);  // hs0 j1
            gll16(row + 32, m0b + (uint32_t)(ks*4 + 2) * 1024);  // hs1 j0
            gll16(row + 48, m0b + (uint32_t)(ks*4 + 3) * 1024);  // hs1 j1
        }
    };

    issue_tile(0);
    issue_tile(1);

    #pragma unroll
    for (int p = 0; p < 16; ++p) {
        // retire tile p; keep tile p+1 (+ stores) in flight.
        // younger-than-T(p): p=0: T1=16; p=1: T2+S0=20; p>=2: S(p-2)+T(p+1)+S(p-1)=24;
        // p=15: S13+S14=8.
        if      (p == 0)  wait_vmcnt<16>();
        else if (p == 1)  wait_vmcnt<20>();
        else if (p == 15) wait_vmcnt<8>();
        else              wait_vmcnt<24>();

        const uint32_t tb = (uint32_t)(p & 1) * 16384;
        f32x4 acc[4];
        #pragma unroll
        for (int t = 0; t < 4; ++t) acc[t] = (f32x4){0.f, 0.f, 0.f, 0.f};

        #pragma unroll
        for (int s = 0; s < 8; ++s) {
            const uint8_t* pb = lds_raw + tb + s*2048 + q*512 + c*16;
            f32x4 xa = *(const f32x4*)(pb);        // kk-local q*8+0..3
            f32x4 xb = *(const f32x4*)(pb + 256);  // kk-local q*8+4..7
            bf16x8 bf;
            uint32_t* bp = (uint32_t*)&bf;
            bp[0] = pack2_bf16(xa[0], xa[1]);
            bp[1] = pack2_bf16(xa[2], xa[3]);
            bp[2] = pack2_bf16(xb[0], xb[1]);
            bp[3] = pack2_bf16(xb[2], xb[3]);
            #pragma unroll
            for (int t = 0; t < 4; ++t)
                acc[t] = __builtin_amdgcn_mfma_f32_16x16x32_bf16(aw[t][s], bf, acc[t], 0, 0, 0);
        }

        if (p + 2 < 16) issue_tile(p + 2);   // before stores: keeps queue order T,S

        // store: D col=c -> (site n0+p*4+sl, batch b0+bb); D row o = t*16+q*4+r
        const int n = n0 + p*4 + sl;
        float* op = out + ((size_t)(b0 + bb) * N_SITES + n) * OUT_DIM + q*4;
        #pragma unroll
        for (int t = 0; t < 4; ++t)
            *(f32x4*)(op + t*16) = acc[t] + bias_r[t];
    }
}

extern "C" void kernel_launch(void* const* d_in, const int* in_sizes, int n_in,
                              void* d_out, int out_size, void* d_ws, size_t ws_size,
                              hipStream_t stream) {
    const float* x       = (const float*)d_in[0];
    const float* W       = (const float*)d_in[1];
    const float* bias    = (const float*)d_in[2];
    const int*   kernel2 = (const int*)d_in[3];
    float* out = (float*)d_out;

    // 64 site-groups x 16 batch-groups = 1024 single-wave blocks (4/CU)
    conv_async_kernel<<<1024, 64, 0, stream>>>(x, W, bias, kernel2, out);
}